// Round 10
// baseline (544.702 us; speedup 1.0000x reference)
//
#include <hip/hip_runtime.h>
#include <hip/hip_bf16.h>
#include <stdint.h>

typedef __bf16 bf16x8 __attribute__((ext_vector_type(8)));
typedef float  f32x4  __attribute__((ext_vector_type(4)));

#define HID   1024
#define SEQT  64
#define BATCH 32
#define GATES 4096
#define ROWS  2048
#define VOCAB 32000
#define HSLAB (64 * 32 * 16)         // 32768 elems per h time-slab (block layout)
#define AGT __HIP_MEMORY_SCOPE_AGENT

__device__ __forceinline__ unsigned short f2bf(float f) {
    union { float f; unsigned u; } v; v.f = f;
    unsigned u = v.u + 0x7FFFu + ((v.u >> 16) & 1u);   // RNE
    return (unsigned short)(u >> 16);
}

__device__ __forceinline__ float sigm(float x) { return 1.f / (1.f + expf(-x)); }

__device__ __forceinline__ void gload_lds16(const void* g, void* l) {
    __builtin_amdgcn_global_load_lds(
        (const __attribute__((address_space(1))) unsigned int*)g,
        (__attribute__((address_space(3))) unsigned int*)l,
        16, 0, 0);
}

__device__ __forceinline__ ushort4 cvt4(float4 v) {
    ushort4 o;
    o.x = f2bf(v.x); o.y = f2bf(v.y); o.z = f2bf(v.z); o.w = f2bf(v.w);
    return o;
}

// ------------- fused prologue: embed + Wx0 cvt + state/flag init -------------
__global__ __launch_bounds__(256) void prologue_k(
    const int* __restrict__ x, const float* __restrict__ embW,
    unsigned short* __restrict__ eb,
    const float* __restrict__ Wx0, unsigned short* __restrict__ Wx0b,
    const float* __restrict__ h0, const float* __restrict__ h1,
    unsigned short* __restrict__ h0b, unsigned short* __restrict__ h1b,
    int* __restrict__ bar)
{
    const int bid = blockIdx.x, tid = threadIdx.x;   // grid 2048 x 256
    // embedding row
    const float4* src = (const float4*)(embW + (size_t)x[bid] * HID);
    ((ushort4*)(eb + (size_t)bid * HID))[tid] = cvt4(src[tid]);
    // Wx0 f32->bf16: 1,048,576 float4s = 2048 blocks * 512
    int base = bid * 512 + tid;
    ((ushort4*)Wx0b)[base]       = cvt4(((const float4*)Wx0)[base]);
    ((ushort4*)Wx0b)[base + 256] = cvt4(((const float4*)Wx0)[base + 256]);
    // state init (block layout) + flag zero
    int i = bid * 256 + tid;
    if (i < 32768) {
        int blk = i >> 9, b = (i >> 4) & 31, w = i & 15;
        int col = blk * 16 + w;
        h0b[i] = f2bf(h0[b * HID + col]);
        h1b[i] = f2bf(h1[b * HID + col]);
        if (i < 8192) bar[i] = 0;
    }
}

// ---------------- NT GEMM for gx0: 256x128 tiles, BK=64, XOR-swizzled LDS ----------------
// 256 blocks x 512 thr; XCD-chunked: each XCD owns 4 N-panels (B reuse in L2).
__global__ __launch_bounds__(512) void gemm_bt(
    const unsigned short* __restrict__ A,      // [2048][1024] bf16
    const unsigned short* __restrict__ B,      // [4096][1024] bf16
    float* __restrict__ C,                     // [2048][4096] f32
    const float* __restrict__ bias0,
    const float* __restrict__ bias1)
{
    __shared__ unsigned short As[256 * 64];    // 32KB: 256 rows x 128B
    __shared__ unsigned short Bs[128 * 64];    // 16KB: 128 rows x 128B
    const int tid  = threadIdx.x;
    const int lane = tid & 63;
    const int wave = tid >> 6;             // 0..7
    const int wr   = wave >> 1;            // 0..3 (M)
    const int wc   = wave & 1;             // 0..1 (N)
    const int lr   = lane & 15;
    const int lk2  = (lane >> 4) * 16;     // byte offset of 8-elem k-group

    const int per = 256 >> 3;              // 32
    const int wid = ((int)blockIdx.x & 7) * per + ((int)blockIdx.x >> 3);
    const int bm  = (wid & 7) << 8;        // 8 M panels of 256
    const int bn  = (wid >> 3) << 7;       // 32 N panels of 128

    f32x4 acc[4][4];
    #pragma unroll
    for (int m = 0; m < 4; ++m)
        #pragma unroll
        for (int n = 0; n < 4; ++n) acc[m][n] = 0.f;

    for (int kt = 0; kt < HID; kt += 64) {
        __syncthreads();
        #pragma unroll
        for (int i = 0; i < 4; ++i) {      // A: 2048 chunks of 16B
            int ch = tid + i * 512;
            int row = ch >> 3, ck = ch & 7;
            int e = kt + ((ck ^ (row & 7)) << 3);   // source-permuted k-granule
            gload_lds16(A + (size_t)(bm + row) * HID + e, (char*)As + ch * 16);
        }
        #pragma unroll
        for (int i = 0; i < 2; ++i) {      // B: 1024 chunks of 16B
            int ch = tid + i * 512;
            int row = ch >> 3, ck = ch & 7;
            int e = kt + ((ck ^ (row & 7)) << 3);
            gload_lds16(B + (size_t)(bn + row) * HID + e, (char*)Bs + ch * 16);
        }
        __syncthreads();
        #pragma unroll
        for (int kh = 0; kh < 2; ++kh) {
            bf16x8 af[4], bfr[4];
            #pragma unroll
            for (int m = 0; m < 4; ++m) {
                int row = wr * 64 + m * 16 + lr;
                af[m] = *(const bf16x8*)((char*)As + row * 128 +
                         ((kh * 64 + lk2) ^ ((row & 7) << 4)));
            }
            #pragma unroll
            for (int n = 0; n < 4; ++n) {
                int row = wc * 64 + n * 16 + lr;
                bfr[n] = *(const bf16x8*)((char*)Bs + row * 128 +
                         ((kh * 64 + lk2) ^ ((row & 7) << 4)));
            }
            #pragma unroll
            for (int m = 0; m < 4; ++m)
                #pragma unroll
                for (int n = 0; n < 4; ++n)
                    acc[m][n] = __builtin_amdgcn_mfma_f32_16x16x32_bf16(
                        af[m], bfr[n], acc[m][n], 0, 0, 0);
        }
    }

    const int row0 = bm + wr * 64, col0 = bn + wc * 64;
    #pragma unroll
    for (int n = 0; n < 4; ++n) {
        int col = col0 + n * 16 + lr;
        float badd = bias0[col] + bias1[col];
        #pragma unroll
        for (int m = 0; m < 4; ++m) {
            #pragma unroll
            for (int j = 0; j < 4; ++j) {
                int row = row0 + m * 16 + (lane >> 4) * 4 + j;
                C[(size_t)row * GATES + col] = acc[m][n][j] + badd;
            }
        }
    }
}

// ---------------- fused persistent recurrence, 4 roles, XCD-local ----------------
// XCD {0,1}=L0 | {2,3}=L1x | {4,5}=L1h | {6,7}=fcW convert.
// L1h: combined poll (grp1+grp2 in one loop, one observation RTT) and part[t]
// prefetch issued before stage (drained for free by the stage barrier's vmcnt(0)).
__global__ __launch_bounds__(256, 1) void lstm_fused_k(
    const float* __restrict__ Wh0f,
    const float* __restrict__ Wx1f,
    const float* __restrict__ Wh1f,
    const float* __restrict__ gx0,
    const float* __restrict__ bx1,
    const float* __restrict__ bh1,
    const unsigned short* __restrict__ h0b,
    const unsigned short* __restrict__ h1b,
    const float* __restrict__ c0i,
    const float* __restrict__ c1i,
    unsigned short* __restrict__ y0x,          // [64][64][32][16] bf16
    unsigned short* __restrict__ y1x,          // [64][64][32][16] bf16
    float* __restrict__ part,                  // [64][4][64][32][16] f32
    float* __restrict__ h0f, float* __restrict__ c0f,
    float* __restrict__ h1f, float* __restrict__ c1f,
    int* __restrict__ bar,
    const float* __restrict__ fcW,
    unsigned short* __restrict__ fcWb)
{
    const int tid  = threadIdx.x;
    const int bid  = blockIdx.x;
    const int xcd  = bid & 7;
    const int role = xcd >> 1;                 // 0=L0, 1=L1x, 2=L1h, 3=riders
    const int wg   = ((bid >> 3) << 1) | (xcd & 1);   // 0..63 within role

    // ---- free-riders: fcW f32 -> bf16 (cross-kernel visibility is implicit) ----
    if (role == 3) {
        int base = wg * 256 + tid;                 // 16384 threads
        const float4* f4 = (const float4*)fcW;
        uint4* o4 = (uint4*)fcWb;
        const int n8 = VOCAB * HID / 8;
        for (int i = base; i < n8; i += 16384) {
            float4 v0 = f4[2 * i], v1 = f4[2 * i + 1];
            uint4 o;
            o.x = (unsigned)f2bf(v0.x) | ((unsigned)f2bf(v0.y) << 16);
            o.y = (unsigned)f2bf(v0.z) | ((unsigned)f2bf(v0.w) << 16);
            o.z = (unsigned)f2bf(v1.x) | ((unsigned)f2bf(v1.y) << 16);
            o.w = (unsigned)f2bf(v1.z) | ((unsigned)f2bf(v1.w) << 16);
            o4[i] = o;
        }
        return;
    }

    // kill stale cache lines from the previous graph replay
    __builtin_amdgcn_fence(__ATOMIC_ACQUIRE, "agent");

    __shared__ char smem[65536 + 8192];
    float* pre = (float*)(smem + 65536);
    const int lane = tid & 63;
    const int wave = tid >> 6;
    const int lr   = lane & 15;
    const int lk8  = (lane >> 4) * 8;
    const int r0   = lr, r1 = 16 + lr;
    const int kby  = (lane >> 4) * 16;
    const int eb_  = tid >> 3;
    const int ecp  = (tid & 7) * 2;
    const int ecol = wg * 16 + ecp;

    // weights: load f32, convert, force resident
    bf16x8 wf[32];
    {
        const float* Wsrc = (role == 0) ? Wh0f : (role == 1) ? Wx1f : Wh1f;
        const float* p = Wsrc + (size_t)(wave * HID + wg * 16 + lr) * HID + lk8;
        #pragma unroll
        for (int kk = 0; kk < 32; ++kk) {
            float4 v0 = *(const float4*)(p + kk * 32);
            float4 v1 = *(const float4*)(p + kk * 32 + 4);
            union { bf16x8 v; unsigned short s[8]; } u;
            u.s[0] = f2bf(v0.x); u.s[1] = f2bf(v0.y);
            u.s[2] = f2bf(v0.z); u.s[3] = f2bf(v0.w);
            u.s[4] = f2bf(v1.x); u.s[5] = f2bf(v1.y);
            u.s[6] = f2bf(v1.z); u.s[7] = f2bf(v1.w);
            wf[kk] = u.v;
        }
        #pragma unroll
        for (int kk = 0; kk < 32; ++kk) asm volatile("" : "+v"(wf[kk]));
    }

    // stage 64KB h-slab from block layout into swizzled LDS image
    auto stage_g = [&](const unsigned short* src) {
        #pragma unroll
        for (int j = 0; j < 16; ++j) {
            int base = wave * 16384 + j * 1024;    // wave-uniform LDS dest
            int d = base + lane * 16;
            int r = d >> 11;
            int cb = (d & 2047) ^ ((r & 7) << 4);
            int e0 = cb >> 1;
            int g = (((e0 >> 4) * 32 + r) * 16 + (e0 & 15)) * 2;
            gload_lds16((const char*)src + g, smem + base);
        }
    };
    auto mm = [&](f32x4& A0, f32x4& A1) {
        #pragma unroll
        for (int kk = 0; kk < 32; ++kk) {
            int k2 = kk * 64 + kby;
            bf16x8 x0 = *(const bf16x8*)(smem + r0 * 2048 + (k2 ^ ((r0 & 7) << 4)));
            bf16x8 x1 = *(const bf16x8*)(smem + r1 * 2048 + (k2 ^ ((r1 & 7) << 4)));
            A0 = __builtin_amdgcn_mfma_f32_16x16x32_bf16(x0, wf[kk], A0, 0, 0, 0);
            A1 = __builtin_amdgcn_mfma_f32_16x16x32_bf16(x1, wf[kk], A1, 0, 0, 0);
        }
    };
    auto spill = [&](const f32x4& a0, const f32x4& a1) {
        float* pg = pre + wave * 512;
        #pragma unroll
        for (int j = 0; j < 4; ++j) {
            pg[((lane >> 4) * 4 + j) * 16 + lr]        = a0[j];
            pg[((lane >> 4) * 4 + j + 16) * 16 + lr]   = a1[j];
        }
    };
    // all-wave parallel poll: every wave checks all 64 flags of group `grp`
    auto pollge = [&](int grp, int val) {
        for (;;) {
            int f = __hip_atomic_load(&bar[(grp * 64 + lane) * 32],
                                      __ATOMIC_RELAXED, AGT);
            if (__all(f >= val)) break;
            __builtin_amdgcn_s_sleep(1);
        }
    };

    if (role == 0) {                               // ---------- L0 ----------
        float creg0, creg1;
        { float2 c2 = *(const float2*)&c0i[eb_ * HID + ecol]; creg0 = c2.x; creg1 = c2.y; }
        for (int t = 0; t < SEQT; ++t) {
            float2 gpre[4];
            const float* gxr = gx0 + (size_t)(t * BATCH + eb_) * GATES + ecol;
            #pragma unroll
            for (int g = 0; g < 4; ++g) gpre[g] = *(const float2*)(gxr + g * HID);
            if (t > 0) pollge(0, t);
            asm volatile("" ::: "memory");
            stage_g(t == 0 ? h0b : y0x + (size_t)(t - 1) * HSLAB);
            __syncthreads();
            f32x4 a0 = 0.f, a1 = 0.f;
            mm(a0, a1);
            spill(a0, a1);
            __syncthreads();
            float2 P[4];
            #pragma unroll
            for (int g = 0; g < 4; ++g) {
                float2 pr = *(const float2*)&pre[(g * 32 + eb_) * 16 + ecp];
                P[g].x = pr.x + gpre[g].x; P[g].y = pr.y + gpre[g].y;
            }
            float i0 = sigm(P[0].x), fg0 = sigm(P[1].x), o0 = sigm(P[2].x), n0 = tanhf(P[3].x);
            float i1 = sigm(P[0].y), fg1 = sigm(P[1].y), o1 = sigm(P[2].y), n1 = tanhf(P[3].y);
            float cn0 = fg0 * creg0 + i0 * n0, cn1 = fg1 * creg1 + i1 * n1;
            float hv0 = o0 * tanhf(cn0), hv1 = o1 * tanhf(cn1);
            creg0 = cn0; creg1 = cn1;
            unsigned pk = (unsigned)f2bf(hv0) | ((unsigned)f2bf(hv1) << 16);
            __hip_atomic_store(
                (unsigned*)&y0x[(size_t)t * HSLAB + (wg * 32 + eb_) * 16 + ecp],
                pk, __ATOMIC_RELAXED, AGT);
            if (t == SEQT - 1) {
                *(float2*)&h0f[eb_ * HID + ecol] = make_float2(hv0, hv1);
                *(float2*)&c0f[eb_ * HID + ecol] = make_float2(cn0, cn1);
            }
            __syncthreads();                       // drain publishes of all waves
            if (tid == 0)
                __hip_atomic_store(&bar[wg * 32], t + 1, __ATOMIC_RELAXED, AGT);
        }
    } else if (role == 1) {                        // ---------- L1x ----------
        for (int t = 0; t < SEQT; ++t) {
            pollge(0, t + 1);
            asm volatile("" ::: "memory");
            stage_g(y0x + (size_t)t * HSLAB);
            __syncthreads();
            f32x4 a0 = 0.f, a1 = 0.f;
            mm(a0, a1);
            {   // contiguous per-wave partial block [t][wave][wg][32][16]
                float* pb = part + (((size_t)(t * 4 + wave) * 64 + wg) * 32) * 16;
                int brow = (lane >> 4) * 4;
                #pragma unroll
                for (int j = 0; j < 4; ++j) {
                    __hip_atomic_store(pb + (brow + j) * 16 + lr,      a0[j],
                                       __ATOMIC_RELAXED, AGT);
                    __hip_atomic_store(pb + (brow + j + 16) * 16 + lr, a1[j],
                                       __ATOMIC_RELAXED, AGT);
                }
            }
            __syncthreads();
            if (tid == 0)
                __hip_atomic_store(&bar[(64 + wg) * 32], t + 1, __ATOMIC_RELAXED, AGT);
        }
    } else {                                       // ---------- L1h ----------
        float creg0, creg1;
        { float2 c2 = *(const float2*)&c1i[eb_ * HID + ecol]; creg0 = c2.x; creg1 = c2.y; }
        float2 b1r[4];
        #pragma unroll
        for (int g = 0; g < 4; ++g) {
            float2 a = *(const float2*)&bx1[g * HID + ecol];
            float2 b = *(const float2*)&bh1[g * HID + ecol];
            b1r[g].x = a.x + b.x; b1r[g].y = a.y + b.y;
        }
        for (int t = 0; t < SEQT; ++t) {
            // combined poll: grp1 >= t+1 (part[t]+y0 consumed by L1x done)
            // and grp2 >= t (own y1x[t-1] published) in ONE observation loop
            {
                const int tneed = (t > 0) ? t : (int)0x80000000;
                for (;;) {
                    int fa = __hip_atomic_load(&bar[(64 + lane) * 32],
                                               __ATOMIC_RELAXED, AGT);
                    int fb = __hip_atomic_load(&bar[(128 + lane) * 32],
                                               __ATOMIC_RELAXED, AGT);
                    if (__all((fa >= t + 1) & (fb >= tneed))) break;
                    __builtin_amdgcn_s_sleep(1);
                }
            }
            asm volatile("" ::: "memory");
            // prefetch part[t] into regs; drained by the stage barrier's vmcnt(0)
            float2 px[4];
            #pragma unroll
            for (int g = 0; g < 4; ++g)
                px[g] = *(const float2*)(part +
                    ((((size_t)(t * 4 + g) * 64 + wg) * 32 + eb_) * 16 + ecp));
            stage_g(t == 0 ? h1b : y1x + (size_t)(t - 1) * HSLAB);
            __syncthreads();
            f32x4 a0 = 0.f, a1 = 0.f;
            mm(a0, a1);
            spill(a0, a1);
            __syncthreads();
            float2 P[4];
            #pragma unroll
            for (int g = 0; g < 4; ++g) {
                float2 pr = *(const float2*)&pre[(g * 32 + eb_) * 16 + ecp];
                P[g].x = pr.x + px[g].x + b1r[g].x;
                P[g].y = pr.y + px[g].y + b1r[g].y;
            }
            float i0 = sigm(P[0].x), fg0 = sigm(P[1].x), o0 = sigm(P[2].x), n0 = tanhf(P[3].x);
            float i1 = sigm(P[0].y), fg1 = sigm(P[1].y), o1 = sigm(P[2].y), n1 = tanhf(P[3].y);
            float cn0 = fg0 * creg0 + i0 * n0, cn1 = fg1 * creg1 + i1 * n1;
            float hv0 = o0 * tanhf(cn0), hv1 = o1 * tanhf(cn1);
            creg0 = cn0; creg1 = cn1;
            unsigned pk = (unsigned)f2bf(hv0) | ((unsigned)f2bf(hv1) << 16);
            __hip_atomic_store(
                (unsigned*)&y1x[(size_t)t * HSLAB + (wg * 32 + eb_) * 16 + ecp],
                pk, __ATOMIC_RELAXED, AGT);
            if (t == SEQT - 1) {
                *(float2*)&h1f[eb_ * HID + ecol] = make_float2(hv0, hv1);
                *(float2*)&c1f[eb_ * HID + ecol] = make_float2(cn0, cn1);
            }
            __syncthreads();
            if (tid == 0)
                __hip_atomic_store(&bar[(128 + wg) * 32], t + 1, __ATOMIC_RELAXED, AGT);
        }
    }
}

// ---------------- FC: logits = y1 @ fcW^T + fcb, 256x128 tiles ----------------
// BK=64, 128B LDS rows with XOR-16 swizzle (conflict-free ds_read_b128).
__global__ __launch_bounds__(512) void fc_k(
    const unsigned short* __restrict__ y1x,
    const unsigned short* __restrict__ fcWb,
    const float* __restrict__ fcb,
    float* __restrict__ logits)
{
    __shared__ unsigned short As[256 * 64];    // 32KB: 256 rows x 128B
    __shared__ unsigned short Bs[128 * 64];    // 16KB: 128 rows x 128B
    const int tid  = threadIdx.x;
    const int lane = tid & 63;
    const int wave = tid >> 6;             // 0..7
    const int wr   = wave >> 1;            // 0..3 (M)
    const int wc   = wave & 1;             // 0..1 (N)
    const int lr   = lane & 15;
    const int lk2  = (lane >> 4) * 16;     // byte offset of 8-elem k-group

    const int per = 2000 >> 3;             // 250
    const int wid = ((int)blockIdx.x & 7) * per + ((int)blockIdx.x >> 3);
    const int bm  = (wid & 7) << 8;        // M tile: 8 panels of 256
    const int bn  = (wid >> 3) << 7;       // N tile: 250 panels of 128

    f32x4 acc[4][4];
    #pragma unroll
    for (int m = 0; m < 4; ++m)
        #pragma unroll
        for (int n = 0; n < 4; ++n) acc[m][n] = 0.f;

    for (int kt = 0; kt < HID; kt += 64) {
        __syncthreads();
        #pragma unroll
        for (int i = 0; i < 4; ++i) {      // A: 2048 chunks of 16B
            int ch = tid + i * 512;
            int row = ch >> 3, ck = ch & 7;
            int R = bm + row;
            int e = kt + ((ck ^ (row & 7)) << 3);   // source-permuted k-granule
            const char* asrc = (const char*)y1x +
                ((((size_t)(R >> 5) * 64 + (e >> 4)) * 32 + (R & 31)) * 16 + (e & 15)) * 2;
            gload_lds16(asrc, (char*)As + ch * 16);
        }
        #pragma unroll
        for (int i = 0; i < 2; ++i) {      // B: 1024 chunks of 16B
            int ch = tid + i * 512;
            int row = ch >> 3, ck = ch & 7;
            int e = kt + ((ck ^ (row & 7)) << 3);
            gload_lds16(fcWb + (size_t)(bn + row) * HID + e, (char*)Bs + ch * 16);
        }
        __syncthreads();
        #pragma unroll
        for (int kh = 0; kh < 2; ++kh) {
            bf16x8 af[4], bfr[4];
            #pragma unroll
            for (int m = 0; m < 4; ++m) {
                int row = wr * 64 + m * 16 + lr;
                af[m] = *(const bf16x8*)((char*)As + row * 128 +
                         ((kh * 64 + lk2) ^ ((row & 7) << 4)));
            }
            #pragma unroll
            for (int n = 0; n < 4; ++n) {
                int row = wc * 64 + n * 16 + lr;
                bfr[n] = *(const bf16x8*)((char*)Bs + row * 128 +
                         ((kh * 64 + lk2) ^ ((row & 7) << 4)));
            }
            #pragma unroll
            for (int m = 0; m < 4; ++m)
                #pragma unroll
                for (int n = 0; n < 4; ++n)
                    acc[m][n] = __builtin_amdgcn_mfma_f32_16x16x32_bf16(
                        af[m], bfr[n], acc[m][n], 0, 0, 0);
        }
    }

    const int row0 = bm + wr * 64, col0 = bn + wc * 64;
    #pragma unroll
    for (int n = 0; n < 4; ++n) {
        int col = col0 + n * 16 + lr;
        float badd = fcb[col];
        #pragma unroll
        for (int m = 0; m < 4; ++m) {
            #pragma unroll
            for (int j = 0; j < 4; ++j) {
                int row = row0 + m * 16 + (lane >> 4) * 4 + j;
                logits[(size_t)row * VOCAB + col] = acc[m][n][j] + badd;
            }
        }
    }
}

extern "C" void kernel_launch(void* const* d_in, const int* in_sizes, int n_in,
                              void* d_out, int out_size, void* d_ws, size_t ws_size,
                              hipStream_t stream) {
    const int*   x    = (const int*)d_in[0];
    const float* embW = (const float*)d_in[1];
    const float* Wx0  = (const float*)d_in[2];
    const float* Wh0  = (const float*)d_in[3];
    const float* bx0  = (const float*)d_in[4];
    const float* bh0  = (const float*)d_in[5];
    const float* Wx1  = (const float*)d_in[6];
    const float* Wh1  = (const float*)d_in[7];
    const float* bx1  = (const float*)d_in[8];
    const float* bh1  = (const float*)d_in[9];
    const float* fcW  = (const float*)d_in[10];
    const float* fcb  = (const float*)d_in[11];
    const float* h0   = (const float*)d_in[12];
    const float* c0   = (const float*)d_in[13];
    const float* h1   = (const float*)d_in[14];
    const float* c1   = (const float*)d_in[15];

    char* ws = (char*)d_ws;
    size_t off = 0;
    auto alloc = [&](size_t bytes) {
        char* p = ws + off;
        off += (bytes + 255) & ~(size_t)255;
        return p;
    };
    unsigned short* eb    = (unsigned short*)alloc((size_t)ROWS * HID * 2);
    unsigned short* Wx0b  = (unsigned short*)alloc((size_t)GATES * HID * 2);
    unsigned short* fcWb  = (unsigned short*)alloc((size_t)VOCAB * HID * 2);
    float*          gx0   = (float*)alloc((size_t)ROWS * GATES * 4);
    float*          part  = (float*)alloc((size_t)SEQT * 4 * 64 * 32 * 16 * 4);
    unsigned short* y0x   = (unsigned short*)alloc((size_t)SEQT * HSLAB * 2);
    unsigned short* y1x   = (unsigned short*)alloc((size_t)SEQT * HSLAB * 2);
    unsigned short* h0b   = (unsigned short*)alloc((size_t)BATCH * HID * 2);
    unsigned short* h1b   = (unsigned short*)alloc((size_t)BATCH * HID * 2);
    int*            bar   = (int*)alloc((size_t)256 * 32 * 4);
    (void)ws_size; (void)in_sizes; (void)n_in; (void)out_size;

    float* logits = (float*)d_out;
    float* h0f = logits + (size_t)ROWS * VOCAB;
    float* c0f = h0f + BATCH * HID;
    float* h1f = c0f + BATCH * HID;
    float* c1f = h1f + BATCH * HID;

    // 1. fused prologue: embed + Wx0 cvt + state/flag init
    prologue_k<<<ROWS, 256, 0, stream>>>(x, embW, eb, Wx0, Wx0b,
                                         h0, h1, h0b, h1b, bar);
    // 2. gx0 = e @ Wx0^T + (bx0+bh0)  (256x128 BK=64 swizzled tiles)
    gemm_bt<<<256, 512, 0, stream>>>(eb, Wx0b, gx0, bx0, bh0);
    // 3. persistent recurrence, XCD-local roles (+ fcW convert on spare CUs)
    lstm_fused_k<<<256, 256, 0, stream>>>(Wh0, Wx1, Wh1, gx0, bx1, bh1,
                                          h0b, h1b, c0, c1, y0x, y1x, part,
                                          h0f, c0f, h1f, c1f, bar, fcW, fcWb);
    // 4. logits = y1 @ fcW^T + fc_b  (256x128 BK=64 swizzled tiles)
    fc_k<<<2000, 512, 0, stream>>>(y1x, fcWb, fcb, logits);
}

// Round 12
// 529.901 us; speedup vs baseline: 1.0279x; 1.0279x over previous
//
#include <hip/hip_runtime.h>
#include <hip/hip_bf16.h>
#include <stdint.h>

typedef __bf16 bf16x8 __attribute__((ext_vector_type(8)));
typedef float  f32x4  __attribute__((ext_vector_type(4)));

#define HID   1024
#define SEQT  64
#define BATCH 32
#define GATES 4096
#define ROWS  2048
#define VOCAB 32000
#define HSLAB (64 * 32 * 16)         // 32768 elems per h time-slab (block layout)
#define AGT __HIP_MEMORY_SCOPE_AGENT

__device__ __forceinline__ unsigned short f2bf(float f) {
    union { float f; unsigned u; } v; v.f = f;
    unsigned u = v.u + 0x7FFFu + ((v.u >> 16) & 1u);   // RNE
    return (unsigned short)(u >> 16);
}

__device__ __forceinline__ float sigm(float x) { return 1.f / (1.f + expf(-x)); }

__device__ __forceinline__ void gload_lds16(const void* g, void* l) {
    __builtin_amdgcn_global_load_lds(
        (const __attribute__((address_space(1))) unsigned int*)g,
        (__attribute__((address_space(3))) unsigned int*)l,
        16, 0, 0);
}

// hardware barrier that is ALSO a compiler memory barrier (raw
// __builtin_amdgcn_s_barrier is IntrNoMem -> LDS ops may be reordered
// across it; that race broke the previous round's fc pipeline)
#define MBAR() asm volatile("s_barrier" ::: "memory")

__device__ __forceinline__ ushort4 cvt4(float4 v) {
    ushort4 o;
    o.x = f2bf(v.x); o.y = f2bf(v.y); o.z = f2bf(v.z); o.w = f2bf(v.w);
    return o;
}

// ------------- fused prologue: embed + Wx0 cvt + state/flag init -------------
__global__ __launch_bounds__(256) void prologue_k(
    const int* __restrict__ x, const float* __restrict__ embW,
    unsigned short* __restrict__ eb,
    const float* __restrict__ Wx0, unsigned short* __restrict__ Wx0b,
    const float* __restrict__ h0, const float* __restrict__ h1,
    unsigned short* __restrict__ h0b, unsigned short* __restrict__ h1b,
    int* __restrict__ bar)
{
    const int bid = blockIdx.x, tid = threadIdx.x;   // grid 2048 x 256
    // embedding row
    const float4* src = (const float4*)(embW + (size_t)x[bid] * HID);
    ((ushort4*)(eb + (size_t)bid * HID))[tid] = cvt4(src[tid]);
    // Wx0 f32->bf16: 1,048,576 float4s = 2048 blocks * 512
    int base = bid * 512 + tid;
    ((ushort4*)Wx0b)[base]       = cvt4(((const float4*)Wx0)[base]);
    ((ushort4*)Wx0b)[base + 256] = cvt4(((const float4*)Wx0)[base + 256]);
    // state init (block layout) + flag zero
    int i = bid * 256 + tid;
    if (i < 32768) {
        int blk = i >> 9, b = (i >> 4) & 31, w = i & 15;
        int col = blk * 16 + w;
        h0b[i] = f2bf(h0[b * HID + col]);
        h1b[i] = f2bf(h1[b * HID + col]);
        if (i < 8192) bar[i] = 0;
    }
}

// ---------------- NT GEMM for gx0: 256x128 tiles, BK=64, XOR-swizzled LDS ----------------
__global__ __launch_bounds__(512) void gemm_bt(
    const unsigned short* __restrict__ A,      // [2048][1024] bf16
    const unsigned short* __restrict__ B,      // [4096][1024] bf16
    float* __restrict__ C,                     // [2048][4096] f32
    const float* __restrict__ bias0,
    const float* __restrict__ bias1)
{
    __shared__ unsigned short As[256 * 64];    // 32KB: 256 rows x 128B
    __shared__ unsigned short Bs[128 * 64];    // 16KB: 128 rows x 128B
    const int tid  = threadIdx.x;
    const int lane = tid & 63;
    const int wave = tid >> 6;             // 0..7
    const int wr   = wave >> 1;            // 0..3 (M)
    const int wc   = wave & 1;             // 0..1 (N)
    const int lr   = lane & 15;
    const int lk2  = (lane >> 4) * 16;     // byte offset of 8-elem k-group

    const int per = 256 >> 3;              // 32
    const int wid = ((int)blockIdx.x & 7) * per + ((int)blockIdx.x >> 3);
    const int bm  = (wid & 7) << 8;        // 8 M panels of 256
    const int bn  = (wid >> 3) << 7;       // 32 N panels of 128

    f32x4 acc[4][4];
    #pragma unroll
    for (int m = 0; m < 4; ++m)
        #pragma unroll
        for (int n = 0; n < 4; ++n) acc[m][n] = 0.f;

    for (int kt = 0; kt < HID; kt += 64) {
        __syncthreads();
        #pragma unroll
        for (int i = 0; i < 4; ++i) {      // A: 2048 chunks of 16B
            int ch = tid + i * 512;
            int row = ch >> 3, ck = ch & 7;
            int e = kt + ((ck ^ (row & 7)) << 3);   // source-permuted k-granule
            gload_lds16(A + (size_t)(bm + row) * HID + e, (char*)As + ch * 16);
        }
        #pragma unroll
        for (int i = 0; i < 2; ++i) {      // B: 1024 chunks of 16B
            int ch = tid + i * 512;
            int row = ch >> 3, ck = ch & 7;
            int e = kt + ((ck ^ (row & 7)) << 3);
            gload_lds16(B + (size_t)(bn + row) * HID + e, (char*)Bs + ch * 16);
        }
        __syncthreads();
        #pragma unroll
        for (int kh = 0; kh < 2; ++kh) {
            bf16x8 af[4], bfr[4];
            #pragma unroll
            for (int m = 0; m < 4; ++m) {
                int row = wr * 64 + m * 16 + lr;
                af[m] = *(const bf16x8*)((char*)As + row * 128 +
                         ((kh * 64 + lk2) ^ ((row & 7) << 4)));
            }
            #pragma unroll
            for (int n = 0; n < 4; ++n) {
                int row = wc * 64 + n * 16 + lr;
                bfr[n] = *(const bf16x8*)((char*)Bs + row * 128 +
                         ((kh * 64 + lk2) ^ ((row & 7) << 4)));
            }
            #pragma unroll
            for (int m = 0; m < 4; ++m)
                #pragma unroll
                for (int n = 0; n < 4; ++n)
                    acc[m][n] = __builtin_amdgcn_mfma_f32_16x16x32_bf16(
                        af[m], bfr[n], acc[m][n], 0, 0, 0);
        }
    }

    const int row0 = bm + wr * 64, col0 = bn + wc * 64;
    #pragma unroll
    for (int n = 0; n < 4; ++n) {
        int col = col0 + n * 16 + lr;
        float badd = bias0[col] + bias1[col];
        #pragma unroll
        for (int m = 0; m < 4; ++m) {
            #pragma unroll
            for (int j = 0; j < 4; ++j) {
                int row = row0 + m * 16 + (lane >> 4) * 4 + j;
                C[(size_t)row * GATES + col] = acc[m][n][j] + badd;
            }
        }
    }
}

// ---------------- fused persistent recurrence, 4 roles, XCD-local (R9 proven) ----------------
// XCD {0,1}=L0 | {2,3}=L1x | {4,5}=L1h | {6,7}=fcW convert.
__global__ __launch_bounds__(256, 1) void lstm_fused_k(
    const float* __restrict__ Wh0f,
    const float* __restrict__ Wx1f,
    const float* __restrict__ Wh1f,
    const float* __restrict__ gx0,
    const float* __restrict__ bx1,
    const float* __restrict__ bh1,
    const unsigned short* __restrict__ h0b,
    const unsigned short* __restrict__ h1b,
    const float* __restrict__ c0i,
    const float* __restrict__ c1i,
    unsigned short* __restrict__ y0x,          // [64][64][32][16] bf16
    unsigned short* __restrict__ y1x,          // [64][64][32][16] bf16
    float* __restrict__ part,                  // [64][4][64][32][16] f32
    float* __restrict__ h0f, float* __restrict__ c0f,
    float* __restrict__ h1f, float* __restrict__ c1f,
    int* __restrict__ bar,
    const float* __restrict__ fcW,
    unsigned short* __restrict__ fcWb)
{
    const int tid  = threadIdx.x;
    const int bid  = blockIdx.x;
    const int xcd  = bid & 7;
    const int role = xcd >> 1;                 // 0=L0, 1=L1x, 2=L1h, 3=riders
    const int wg   = ((bid >> 3) << 1) | (xcd & 1);   // 0..63 within role

    // ---- free-riders: fcW f32 -> bf16 (cross-kernel visibility is implicit) ----
    if (role == 3) {
        int base = wg * 256 + tid;                 // 16384 threads
        const float4* f4 = (const float4*)fcW;
        uint4* o4 = (uint4*)fcWb;
        const int n8 = VOCAB * HID / 8;
        for (int i = base; i < n8; i += 16384) {
            float4 v0 = f4[2 * i], v1 = f4[2 * i + 1];
            uint4 o;
            o.x = (unsigned)f2bf(v0.x) | ((unsigned)f2bf(v0.y) << 16);
            o.y = (unsigned)f2bf(v0.z) | ((unsigned)f2bf(v0.w) << 16);
            o.z = (unsigned)f2bf(v1.x) | ((unsigned)f2bf(v1.y) << 16);
            o.w = (unsigned)f2bf(v1.z) | ((unsigned)f2bf(v1.w) << 16);
            o4[i] = o;
        }
        return;
    }

    // kill stale cache lines from the previous graph replay
    __builtin_amdgcn_fence(__ATOMIC_ACQUIRE, "agent");

    __shared__ char smem[65536 + 8192];
    float* pre = (float*)(smem + 65536);
    const int lane = tid & 63;
    const int wave = tid >> 6;
    const int lr   = lane & 15;
    const int lk8  = (lane >> 4) * 8;
    const int r0   = lr, r1 = 16 + lr;
    const int kby  = (lane >> 4) * 16;
    const int eb_  = tid >> 3;
    const int ecp  = (tid & 7) * 2;
    const int ecol = wg * 16 + ecp;

    // weights: load f32, convert, force resident
    bf16x8 wf[32];
    {
        const float* Wsrc = (role == 0) ? Wh0f : (role == 1) ? Wx1f : Wh1f;
        const float* p = Wsrc + (size_t)(wave * HID + wg * 16 + lr) * HID + lk8;
        #pragma unroll
        for (int kk = 0; kk < 32; ++kk) {
            float4 v0 = *(const float4*)(p + kk * 32);
            float4 v1 = *(const float4*)(p + kk * 32 + 4);
            union { bf16x8 v; unsigned short s[8]; } u;
            u.s[0] = f2bf(v0.x); u.s[1] = f2bf(v0.y);
            u.s[2] = f2bf(v0.z); u.s[3] = f2bf(v0.w);
            u.s[4] = f2bf(v1.x); u.s[5] = f2bf(v1.y);
            u.s[6] = f2bf(v1.z); u.s[7] = f2bf(v1.w);
            wf[kk] = u.v;
        }
        #pragma unroll
        for (int kk = 0; kk < 32; ++kk) asm volatile("" : "+v"(wf[kk]));
    }

    // stage 64KB h-slab from block layout into swizzled LDS image
    auto stage_g = [&](const unsigned short* src) {
        #pragma unroll
        for (int j = 0; j < 16; ++j) {
            int base = wave * 16384 + j * 1024;    // wave-uniform LDS dest
            int d = base + lane * 16;
            int r = d >> 11;
            int cb = (d & 2047) ^ ((r & 7) << 4);
            int e0 = cb >> 1;
            int g = (((e0 >> 4) * 32 + r) * 16 + (e0 & 15)) * 2;
            gload_lds16((const char*)src + g, smem + base);
        }
    };
    auto mm = [&](f32x4& A0, f32x4& A1) {
        #pragma unroll
        for (int kk = 0; kk < 32; ++kk) {
            int k2 = kk * 64 + kby;
            bf16x8 x0 = *(const bf16x8*)(smem + r0 * 2048 + (k2 ^ ((r0 & 7) << 4)));
            bf16x8 x1 = *(const bf16x8*)(smem + r1 * 2048 + (k2 ^ ((r1 & 7) << 4)));
            A0 = __builtin_amdgcn_mfma_f32_16x16x32_bf16(x0, wf[kk], A0, 0, 0, 0);
            A1 = __builtin_amdgcn_mfma_f32_16x16x32_bf16(x1, wf[kk], A1, 0, 0, 0);
        }
    };
    auto spill = [&](const f32x4& a0, const f32x4& a1) {
        float* pg = pre + wave * 512;
        #pragma unroll
        for (int j = 0; j < 4; ++j) {
            pg[((lane >> 4) * 4 + j) * 16 + lr]        = a0[j];
            pg[((lane >> 4) * 4 + j + 16) * 16 + lr]   = a1[j];
        }
    };
    // all-wave parallel poll: every wave checks all 64 flags of group `grp`
    auto pollge = [&](int grp, int val) {
        for (;;) {
            int f = __hip_atomic_load(&bar[(grp * 64 + lane) * 32],
                                      __ATOMIC_RELAXED, AGT);
            if (__all(f >= val)) break;
            __builtin_amdgcn_s_sleep(1);
        }
    };

    if (role == 0) {                               // ---------- L0 ----------
        float creg0, creg1;
        { float2 c2 = *(const float2*)&c0i[eb_ * HID + ecol]; creg0 = c2.x; creg1 = c2.y; }
        for (int t = 0; t < SEQT; ++t) {
            float2 gpre[4];
            const float* gxr = gx0 + (size_t)(t * BATCH + eb_) * GATES + ecol;
            #pragma unroll
            for (int g = 0; g < 4; ++g) gpre[g] = *(const float2*)(gxr + g * HID);
            if (t > 0) pollge(0, t);
            asm volatile("" ::: "memory");
            stage_g(t == 0 ? h0b : y0x + (size_t)(t - 1) * HSLAB);
            __syncthreads();
            f32x4 a0 = 0.f, a1 = 0.f;
            mm(a0, a1);
            spill(a0, a1);
            __syncthreads();
            float2 P[4];
            #pragma unroll
            for (int g = 0; g < 4; ++g) {
                float2 pr = *(const float2*)&pre[(g * 32 + eb_) * 16 + ecp];
                P[g].x = pr.x + gpre[g].x; P[g].y = pr.y + gpre[g].y;
            }
            float i0 = sigm(P[0].x), fg0 = sigm(P[1].x), o0 = sigm(P[2].x), n0 = tanhf(P[3].x);
            float i1 = sigm(P[0].y), fg1 = sigm(P[1].y), o1 = sigm(P[2].y), n1 = tanhf(P[3].y);
            float cn0 = fg0 * creg0 + i0 * n0, cn1 = fg1 * creg1 + i1 * n1;
            float hv0 = o0 * tanhf(cn0), hv1 = o1 * tanhf(cn1);
            creg0 = cn0; creg1 = cn1;
            unsigned pk = (unsigned)f2bf(hv0) | ((unsigned)f2bf(hv1) << 16);
            __hip_atomic_store(
                (unsigned*)&y0x[(size_t)t * HSLAB + (wg * 32 + eb_) * 16 + ecp],
                pk, __ATOMIC_RELAXED, AGT);
            if (t == SEQT - 1) {
                *(float2*)&h0f[eb_ * HID + ecol] = make_float2(hv0, hv1);
                *(float2*)&c0f[eb_ * HID + ecol] = make_float2(cn0, cn1);
            }
            __syncthreads();                       // drain publishes of all waves
            if (tid == 0)
                __hip_atomic_store(&bar[wg * 32], t + 1, __ATOMIC_RELAXED, AGT);
        }
    } else if (role == 1) {                        // ---------- L1x ----------
        for (int t = 0; t < SEQT; ++t) {
            pollge(0, t + 1);
            asm volatile("" ::: "memory");
            stage_g(y0x + (size_t)t * HSLAB);
            __syncthreads();
            f32x4 a0 = 0.f, a1 = 0.f;
            mm(a0, a1);
            {   // contiguous per-wave partial block [t][wave][wg][32][16]
                float* pb = part + (((size_t)(t * 4 + wave) * 64 + wg) * 32) * 16;
                int brow = (lane >> 4) * 4;
                #pragma unroll
                for (int j = 0; j < 4; ++j) {
                    __hip_atomic_store(pb + (brow + j) * 16 + lr,      a0[j],
                                       __ATOMIC_RELAXED, AGT);
                    __hip_atomic_store(pb + (brow + j + 16) * 16 + lr, a1[j],
                                       __ATOMIC_RELAXED, AGT);
                }
            }
            __syncthreads();
            if (tid == 0)
                __hip_atomic_store(&bar[(64 + wg) * 32], t + 1, __ATOMIC_RELAXED, AGT);
        }
    } else {                                       // ---------- L1h ----------
        float creg0, creg1;
        { float2 c2 = *(const float2*)&c1i[eb_ * HID + ecol]; creg0 = c2.x; creg1 = c2.y; }
        float2 b1r[4];
        #pragma unroll
        for (int g = 0; g < 4; ++g) {
            float2 a = *(const float2*)&bx1[g * HID + ecol];
            float2 b = *(const float2*)&bh1[g * HID + ecol];
            b1r[g].x = a.x + b.x; b1r[g].y = a.y + b.y;
        }
        for (int t = 0; t < SEQT; ++t) {
            pollge(1, t + 1);
            if (t > 0) pollge(2, t);
            asm volatile("" ::: "memory");
            stage_g(t == 0 ? h1b : y1x + (size_t)(t - 1) * HSLAB);
            __syncthreads();
            f32x4 a0 = 0.f, a1 = 0.f;
            mm(a0, a1);
            spill(a0, a1);
            __syncthreads();
            float2 P[4];
            #pragma unroll
            for (int g = 0; g < 4; ++g) {
                float2 pr = *(const float2*)&pre[(g * 32 + eb_) * 16 + ecp];
                float2 px = *(const float2*)(part +
                    ((((size_t)(t * 4 + g) * 64 + wg) * 32 + eb_) * 16 + ecp));
                P[g].x = pr.x + px.x + b1r[g].x;
                P[g].y = pr.y + px.y + b1r[g].y;
            }
            float i0 = sigm(P[0].x), fg0 = sigm(P[1].x), o0 = sigm(P[2].x), n0 = tanhf(P[3].x);
            float i1 = sigm(P[0].y), fg1 = sigm(P[1].y), o1 = sigm(P[2].y), n1 = tanhf(P[3].y);
            float cn0 = fg0 * creg0 + i0 * n0, cn1 = fg1 * creg1 + i1 * n1;
            float hv0 = o0 * tanhf(cn0), hv1 = o1 * tanhf(cn1);
            creg0 = cn0; creg1 = cn1;
            unsigned pk = (unsigned)f2bf(hv0) | ((unsigned)f2bf(hv1) << 16);
            __hip_atomic_store(
                (unsigned*)&y1x[(size_t)t * HSLAB + (wg * 32 + eb_) * 16 + ecp],
                pk, __ATOMIC_RELAXED, AGT);
            if (t == SEQT - 1) {
                *(float2*)&h1f[eb_ * HID + ecol] = make_float2(hv0, hv1);
                *(float2*)&c1f[eb_ * HID + ecol] = make_float2(cn0, cn1);
            }
            __syncthreads();
            if (tid == 0)
                __hip_atomic_store(&bar[(128 + wg) * 32], t + 1, __ATOMIC_RELAXED, AGT);
        }
    }
}

// ---------------- FC: 256x256 tiles, counted-vmcnt double-buffered pipeline ----------------
// 1000 blocks x 512 thr (8 waves = 2M x 4N of 128x64). BK=64, 16 K-tiles.
// LDS 128KB: A/B x 2 bufs x 2 halves of [128][64] bf16, XOR-16 swizzled rows.
// Per K-tile: MBAR -> issue next-tile half A0 -> s_waitcnt vmcnt(2) (only the 2
// just-issued loads may remain => current tile landed for every wave after the
// 2nd MBAR) -> 4 x 16-MFMA groups with remaining next-tile half-stages
// interleaved. All barriers are asm-with-memory-clobber (compiler fence).
__global__ __launch_bounds__(512) void fc_k(
    const unsigned short* __restrict__ y1x,
    const unsigned short* __restrict__ fcWb,
    const float* __restrict__ fcb,
    float* __restrict__ logits)
{
    __shared__ char smem[131072];
    const int tid  = threadIdx.x;
    const int lane = tid & 63;
    const int wave = tid >> 6;             // 0..7
    const int wr   = wave >> 2;            // 0..1 (M halves of 128)
    const int wc   = wave & 3;             // 0..3 (N quarters of 64)
    const int lr   = lane & 15;
    const int lk2  = (lane >> 4) * 16;     // byte offset of 8-elem k-group

    const int chunk = (int)blockIdx.x >> 3;            // 0..124
    const int wid   = ((int)blockIdx.x & 7) * 125 + chunk;
    const int bm    = (wid % 8) << 8;      // 8 M panels of 256
    const int bn    = (wid / 8) << 8;      // 125 N panels of 256

    // LDS: A(buf,half) at buf*32768 + half*16384; B at +65536.
    auto stage_half = [&](int hh, int kt, int buf) {
        #pragma unroll
        for (int i = 0; i < 2; ++i) {
            int ch = tid + i * 512;                    // 0..1023
            int row = ch >> 3, ck = ch & 7;
            int e = kt * 64 + ((ck ^ (row & 7)) << 3); // source-permuted k-granule
            if (hh < 2) {
                char* dst = smem + buf * 32768 + hh * 16384 + ch * 16;
                int R = bm + hh * 128 + row;
                const char* src = (const char*)y1x +
                    ((((size_t)(R >> 5) * 64 + (e >> 4)) * 32 + (R & 31)) * 16 + (e & 15)) * 2;
                gload_lds16(src, dst);
            } else {
                char* dst = smem + 65536 + buf * 32768 + (hh - 2) * 16384 + ch * 16;
                int R = bn + (hh - 2) * 128 + row;
                gload_lds16(fcWb + (size_t)R * HID + e, dst);
            }
        }
    };

    f32x4 acc[8][4];
    #pragma unroll
    for (int m = 0; m < 8; ++m)
        #pragma unroll
        for (int n = 0; n < 4; ++n) acc[m][n] = 0.f;

    bf16x8 bfr[4][2];
    auto ldb = [&](int buf) {
        const char* Bb = smem + 65536 + buf * 32768 + (wc >> 1) * 16384;
        #pragma unroll
        for (int n = 0; n < 4; ++n)
            #pragma unroll
            for (int kh = 0; kh < 2; ++kh) {
                int rB = (wc & 1) * 64 + n * 16 + lr;
                bfr[n][kh] = *(const bf16x8*)(Bb + rB * 128 +
                              ((kh * 64 + lk2) ^ ((rB & 7) << 4)));
            }
    };
    auto mgrp = [&](int buf, int g) {       // m-pair group g = 0..3
        const char* Ab = smem + buf * 32768 + wr * 16384;
        bf16x8 af[2][2];
        #pragma unroll
        for (int mi = 0; mi < 2; ++mi)
            #pragma unroll
            for (int kh = 0; kh < 2; ++kh) {
                int rA = (g * 2 + mi) * 16 + lr;
                af[mi][kh] = *(const bf16x8*)(Ab + rA * 128 +
                              ((kh * 64 + lk2) ^ ((rA & 7) << 4)));
            }
        __builtin_amdgcn_s_setprio(1);
        #pragma unroll
        for (int mi = 0; mi < 2; ++mi)
            #pragma unroll
            for (int n = 0; n < 4; ++n)
                #pragma unroll
                for (int kh = 0; kh < 2; ++kh)
                    acc[g * 2 + mi][n] = __builtin_amdgcn_mfma_f32_16x16x32_bf16(
                        af[mi][kh], bfr[n][kh], acc[g * 2 + mi][n], 0, 0, 0);
        __builtin_amdgcn_s_setprio(0);
    };

    // prologue: K-tile 0, all 4 halves -> buf 0   (8 loads/thread)
    stage_half(0, 0, 0); stage_half(1, 0, 0);
    stage_half(2, 0, 0); stage_half(3, 0, 0);

    int cbuf = 0;
    for (int kt = 0; kt < 15; ++kt) {
        MBAR();                                    // all prior reads of cbuf^1 done
        stage_half(0, kt + 1, cbuf ^ 1);           // +2 loads (newest)
        asm volatile("s_waitcnt vmcnt(2)" ::: "memory");   // all older (tile kt) landed
        __builtin_amdgcn_sched_barrier(0);
        MBAR();                                    // => landed for EVERY wave
        ldb(cbuf);
        stage_half(1, kt + 1, cbuf ^ 1);
        mgrp(cbuf, 0);
        stage_half(2, kt + 1, cbuf ^ 1);
        mgrp(cbuf, 1);
        stage_half(3, kt + 1, cbuf ^ 1);
        mgrp(cbuf, 2);
        mgrp(cbuf, 3);
        cbuf ^= 1;
    }
    // last K-tile: nothing left to prefetch -> full drain
    MBAR();
    asm volatile("s_waitcnt vmcnt(0)" ::: "memory");
    __builtin_amdgcn_sched_barrier(0);
    MBAR();
    ldb(cbuf);
    mgrp(cbuf, 0); mgrp(cbuf, 1); mgrp(cbuf, 2); mgrp(cbuf, 3);

    const int row0 = bm + wr * 128, col0 = bn + wc * 64;
    #pragma unroll
    for (int n = 0; n < 4; ++n) {
        int col = col0 + n * 16 + lr;
        float badd = fcb[col];
        #pragma unroll
        for (int m = 0; m < 8; ++m) {
            #pragma unroll
            for (int j = 0; j < 4; ++j) {
                int row = row0 + m * 16 + (lane >> 4) * 4 + j;
                logits[(size_t)row * VOCAB + col] = acc[m][n][j] + badd;
            }
        }
    }
}

extern "C" void kernel_launch(void* const* d_in, const int* in_sizes, int n_in,
                              void* d_out, int out_size, void* d_ws, size_t ws_size,
                              hipStream_t stream) {
    const int*   x    = (const int*)d_in[0];
    const float* embW = (const float*)d_in[1];
    const float* Wx0  = (const float*)d_in[2];
    const float* Wh0  = (const float*)d_in[3];
    const float* bx0  = (const float*)d_in[4];
    const float* bh0  = (const float*)d_in[5];
    const float* Wx1  = (const float*)d_in[6];
    const float* Wh1  = (const float*)d_in[7];
    const float* bx1  = (const float*)d_in[8];
    const float* bh1  = (const float*)d_in[9];
    const float* fcW  = (const float*)d_in[10];
    const float* fcb  = (const float*)d_in[11];
    const float* h0   = (const float*)d_in[12];
    const float* c0   = (const float*)d_in[13];
    const float* h1   = (const float*)d_in[14];
    const float* c1   = (const float*)d_in[15];

    char* ws = (char*)d_ws;
    size_t off = 0;
    auto alloc = [&](size_t bytes) {
        char* p = ws + off;
        off += (bytes + 255) & ~(size_t)255;
        return p;
    };
    unsigned short* eb    = (unsigned short*)alloc((size_t)ROWS * HID * 2);
    unsigned short* Wx0b  = (unsigned short*)alloc((size_t)GATES * HID * 2);
    unsigned short* fcWb  = (unsigned short*)alloc((size_t)VOCAB * HID * 2);
    float*          gx0   = (float*)alloc((size_t)ROWS * GATES * 4);
    float*          part  = (float*)alloc((size_t)SEQT * 4 * 64 * 32 * 16 * 4);
    unsigned short* y0x   = (unsigned short*)alloc((size_t)SEQT * HSLAB * 2);
    unsigned short* y1x   = (unsigned short*)alloc((size_t)SEQT * HSLAB * 2);
    unsigned short* h0b   = (unsigned short*)alloc((size_t)BATCH * HID * 2);
    unsigned short* h1b   = (unsigned short*)alloc((size_t)BATCH * HID * 2);
    int*            bar   = (int*)alloc((size_t)256 * 32 * 4);
    (void)ws_size; (void)in_sizes; (void)n_in; (void)out_size;

    float* logits = (float*)d_out;
    float* h0f = logits + (size_t)ROWS * VOCAB;
    float* c0f = h0f + BATCH * HID;
    float* h1f = c0f + BATCH * HID;
    float* c1f = h1f + BATCH * HID;

    // 1. fused prologue: embed + Wx0 cvt + state/flag init
    prologue_k<<<ROWS, 256, 0, stream>>>(x, embW, eb, Wx0, Wx0b,
                                         h0, h1, h0b, h1b, bar);
    // 2. gx0 = e @ Wx0^T + (bx0+bh0)  (256x128 BK=64 swizzled tiles)
    gemm_bt<<<256, 512, 0, stream>>>(eb, Wx0b, gx0, bx0, bh0);
    // 3. persistent recurrence, XCD-local roles (+ fcW convert on spare CUs)
    lstm_fused_k<<<256, 256, 0, stream>>>(Wh0, Wx1, Wh1, gx0, bx1, bh1,
                                          h0b, h1b, c0, c1, y0x, y1x, part,
                                          h0f, c0f, h1f, c1f, bar, fcW, fcWb);
    // 4. logits = y1 @ fcW^T + fc_b  (256x256 counted-vmcnt pipeline)
    fc_k<<<1000, 512, 0, stream>>>(y1x, fcWb, fcb, logits);
}

// Round 13
// 480.751 us; speedup vs baseline: 1.1330x; 1.1022x over previous
//
#include <hip/hip_runtime.h>
#include <hip/hip_bf16.h>
#include <stdint.h>

typedef __bf16 bf16x8 __attribute__((ext_vector_type(8)));
typedef float  f32x4  __attribute__((ext_vector_type(4)));

#define HID   1024
#define SEQT  64
#define BATCH 32
#define GATES 4096
#define ROWS  2048
#define VOCAB 32000
#define HSLAB (64 * 32 * 16)         // 32768 elems per h time-slab (block layout)
#define AGT __HIP_MEMORY_SCOPE_AGENT

__device__ __forceinline__ unsigned short f2bf(float f) {
    union { float f; unsigned u; } v; v.f = f;
    unsigned u = v.u + 0x7FFFu + ((v.u >> 16) & 1u);   // RNE
    return (unsigned short)(u >> 16);
}

__device__ __forceinline__ float sigm(float x) { return 1.f / (1.f + expf(-x)); }

__device__ __forceinline__ void gload_lds16(const void* g, void* l) {
    __builtin_amdgcn_global_load_lds(
        (const __attribute__((address_space(1))) unsigned int*)g,
        (__attribute__((address_space(3))) unsigned int*)l,
        16, 0, 0);
}

// hardware barrier that is ALSO a compiler memory barrier (raw
// __builtin_amdgcn_s_barrier is IntrNoMem -> LDS ops may be reordered across it)
#define MBAR() asm volatile("s_barrier" ::: "memory")

__device__ __forceinline__ ushort4 cvt4(float4 v) {
    ushort4 o;
    o.x = f2bf(v.x); o.y = f2bf(v.y); o.z = f2bf(v.z); o.w = f2bf(v.w);
    return o;
}

// ------------- fused prologue: embed + Wx0 cvt + state/flag init -------------
__global__ __launch_bounds__(256) void prologue_k(
    const int* __restrict__ x, const float* __restrict__ embW,
    unsigned short* __restrict__ eb,
    const float* __restrict__ Wx0, unsigned short* __restrict__ Wx0b,
    const float* __restrict__ h0, const float* __restrict__ h1,
    unsigned short* __restrict__ h0b, unsigned short* __restrict__ h1b,
    int* __restrict__ bar)
{
    const int bid = blockIdx.x, tid = threadIdx.x;   // grid 2048 x 256
    // embedding row
    const float4* src = (const float4*)(embW + (size_t)x[bid] * HID);
    ((ushort4*)(eb + (size_t)bid * HID))[tid] = cvt4(src[tid]);
    // Wx0 f32->bf16: 1,048,576 float4s = 2048 blocks * 512
    int base = bid * 512 + tid;
    ((ushort4*)Wx0b)[base]       = cvt4(((const float4*)Wx0)[base]);
    ((ushort4*)Wx0b)[base + 256] = cvt4(((const float4*)Wx0)[base + 256]);
    // state init (block layout) + flag zero
    int i = bid * 256 + tid;
    if (i < 32768) {
        int blk = i >> 9, b = (i >> 4) & 31, w = i & 15;
        int col = blk * 16 + w;
        h0b[i] = f2bf(h0[b * HID + col]);
        h1b[i] = f2bf(h1[b * HID + col]);
        if (i < 8192) bar[i] = 0;
    }
}

// ---------------- NT GEMM for gx0: 256x128 tiles, BK=64, counted-vmcnt pipeline ----------------
// 256 blocks x 512 thr (1 block/CU). LDS 96KB: A 2bufs x 256x128B, B 2bufs x 128x128B,
// XOR-16 swizzled rows. Per K-tile: MBAR -> issue next-tile A-low (2 loads) ->
// vmcnt(2) (=> all 6 loads of current tile landed) -> MBAR -> compute with
// remaining half-stages interleaved. Same protocol as the proven fc_k pipeline.
__global__ __launch_bounds__(512) void gemm_bt(
    const unsigned short* __restrict__ A,      // [2048][1024] bf16
    const unsigned short* __restrict__ B,      // [4096][1024] bf16
    float* __restrict__ C,                     // [2048][4096] f32
    const float* __restrict__ bias0,
    const float* __restrict__ bias1)
{
    __shared__ char smem[98304];               // A: buf*32768; B: 65536 + buf*16384
    const int tid  = threadIdx.x;
    const int lane = tid & 63;
    const int wave = tid >> 6;             // 0..7
    const int wr   = wave >> 1;            // 0..3 (M)
    const int wc   = wave & 1;             // 0..1 (N)
    const int lr   = lane & 15;
    const int lk2  = (lane >> 4) * 16;     // byte offset of 8-elem k-group

    const int per = 256 >> 3;              // 32
    const int wid = ((int)blockIdx.x & 7) * per + ((int)blockIdx.x >> 3);
    const int bm  = (wid & 7) << 8;        // 8 M panels of 256
    const int bn  = (wid >> 3) << 7;       // 32 N panels of 128

    // A half hh (rows hh*128..+127) of K-tile kt -> buf  (2 loads/thread)
    auto stage_hA = [&](int hh, int kt, int buf) {
        #pragma unroll
        for (int i = 0; i < 2; ++i) {
            int ch = tid + i * 512;                    // 0..1023
            int row = ch >> 3, ck = ch & 7;
            int e = kt * 64 + ((ck ^ (row & 7)) << 3);
            gload_lds16(A + (size_t)(bm + hh * 128 + row) * HID + e,
                        smem + buf * 32768 + hh * 16384 + ch * 16);
        }
    };
    auto stage_B = [&](int kt, int buf) {              // 2 loads/thread
        #pragma unroll
        for (int i = 0; i < 2; ++i) {
            int ch = tid + i * 512;
            int row = ch >> 3, ck = ch & 7;
            int e = kt * 64 + ((ck ^ (row & 7)) << 3);
            gload_lds16(B + (size_t)(bn + row) * HID + e,
                        smem + 65536 + buf * 16384 + ch * 16);
        }
    };

    f32x4 acc[4][4];
    #pragma unroll
    for (int m = 0; m < 4; ++m)
        #pragma unroll
        for (int n = 0; n < 4; ++n) acc[m][n] = 0.f;

    bf16x8 bfr[4][2];
    auto ldb = [&](int buf) {
        const char* Bb = smem + 65536 + buf * 16384;
        #pragma unroll
        for (int n = 0; n < 4; ++n)
            #pragma unroll
            for (int kh = 0; kh < 2; ++kh) {
                int rB = wc * 64 + n * 16 + lr;
                bfr[n][kh] = *(const bf16x8*)(Bb + rB * 128 +
                              ((kh * 64 + lk2) ^ ((rB & 7) << 4)));
            }
    };
    auto mgrp = [&](int buf, int g) {       // m-pair group g = 0..1
        const char* Ab = smem + buf * 32768;
        bf16x8 af[2][2];
        #pragma unroll
        for (int mi = 0; mi < 2; ++mi)
            #pragma unroll
            for (int kh = 0; kh < 2; ++kh) {
                int rA = wr * 64 + (g * 2 + mi) * 16 + lr;
                af[mi][kh] = *(const bf16x8*)(Ab + rA * 128 +
                              ((kh * 64 + lk2) ^ ((rA & 7) << 4)));
            }
        __builtin_amdgcn_s_setprio(1);
        #pragma unroll
        for (int mi = 0; mi < 2; ++mi)
            #pragma unroll
            for (int n = 0; n < 4; ++n)
                #pragma unroll
                for (int kh = 0; kh < 2; ++kh)
                    acc[g * 2 + mi][n] = __builtin_amdgcn_mfma_f32_16x16x32_bf16(
                        af[mi][kh], bfr[n][kh], acc[g * 2 + mi][n], 0, 0, 0);
        __builtin_amdgcn_s_setprio(0);
    };

    // prologue: K-tile 0 -> buf 0 (6 loads/thread)
    stage_hA(0, 0, 0); stage_hA(1, 0, 0); stage_B(0, 0);

    int cbuf = 0;
    for (int kt = 0; kt < 15; ++kt) {
        MBAR();                                    // all prior reads of cbuf^1 done
        stage_hA(0, kt + 1, cbuf ^ 1);             // +2 loads (newest)
        asm volatile("s_waitcnt vmcnt(2)" ::: "memory");   // tile kt fully landed
        __builtin_amdgcn_sched_barrier(0);
        MBAR();                                    // => landed for EVERY wave
        ldb(cbuf);
        stage_hA(1, kt + 1, cbuf ^ 1);
        mgrp(cbuf, 0);
        stage_B(kt + 1, cbuf ^ 1);
        mgrp(cbuf, 1);
        cbuf ^= 1;
    }
    MBAR();
    asm volatile("s_waitcnt vmcnt(0)" ::: "memory");
    __builtin_amdgcn_sched_barrier(0);
    MBAR();
    ldb(cbuf);
    mgrp(cbuf, 0); mgrp(cbuf, 1);

    const int row0 = bm + wr * 64, col0 = bn + wc * 64;
    #pragma unroll
    for (int n = 0; n < 4; ++n) {
        int col = col0 + n * 16 + lr;
        float badd = bias0[col] + bias1[col];
        #pragma unroll
        for (int m = 0; m < 4; ++m) {
            #pragma unroll
            for (int j = 0; j < 4; ++j) {
                int row = row0 + m * 16 + (lane >> 4) * 4 + j;
                C[(size_t)row * GATES + col] = acc[m][n][j] + badd;
            }
        }
    }
}

// ---------------- fused persistent recurrence, 4 roles, XCD-local (R9 proven) ----------------
// XCD {0,1}=L0 | {2,3}=L1x | {4,5}=L1h | {6,7}=fcW convert.
__global__ __launch_bounds__(256, 1) void lstm_fused_k(
    const float* __restrict__ Wh0f,
    const float* __restrict__ Wx1f,
    const float* __restrict__ Wh1f,
    const float* __restrict__ gx0,
    const float* __restrict__ bx1,
    const float* __restrict__ bh1,
    const unsigned short* __restrict__ h0b,
    const unsigned short* __restrict__ h1b,
    const float* __restrict__ c0i,
    const float* __restrict__ c1i,
    unsigned short* __restrict__ y0x,          // [64][64][32][16] bf16
    unsigned short* __restrict__ y1x,          // [64][64][32][16] bf16
    float* __restrict__ part,                  // [64][4][64][32][16] f32
    float* __restrict__ h0f, float* __restrict__ c0f,
    float* __restrict__ h1f, float* __restrict__ c1f,
    int* __restrict__ bar,
    const float* __restrict__ fcW,
    unsigned short* __restrict__ fcWb)
{
    const int tid  = threadIdx.x;
    const int bid  = blockIdx.x;
    const int xcd  = bid & 7;
    const int role = xcd >> 1;                 // 0=L0, 1=L1x, 2=L1h, 3=riders
    const int wg   = ((bid >> 3) << 1) | (xcd & 1);   // 0..63 within role

    // ---- free-riders: fcW f32 -> bf16 (cross-kernel visibility is implicit) ----
    if (role == 3) {
        int base = wg * 256 + tid;                 // 16384 threads
        const float4* f4 = (const float4*)fcW;
        uint4* o4 = (uint4*)fcWb;
        const int n8 = VOCAB * HID / 8;
        for (int i = base; i < n8; i += 16384) {
            float4 v0 = f4[2 * i], v1 = f4[2 * i + 1];
            uint4 o;
            o.x = (unsigned)f2bf(v0.x) | ((unsigned)f2bf(v0.y) << 16);
            o.y = (unsigned)f2bf(v0.z) | ((unsigned)f2bf(v0.w) << 16);
            o.z = (unsigned)f2bf(v1.x) | ((unsigned)f2bf(v1.y) << 16);
            o.w = (unsigned)f2bf(v1.z) | ((unsigned)f2bf(v1.w) << 16);
            o4[i] = o;
        }
        return;
    }

    // kill stale cache lines from the previous graph replay
    __builtin_amdgcn_fence(__ATOMIC_ACQUIRE, "agent");

    __shared__ char smem[65536 + 8192];
    float* pre = (float*)(smem + 65536);
    const int lane = tid & 63;
    const int wave = tid >> 6;
    const int lr   = lane & 15;
    const int lk8  = (lane >> 4) * 8;
    const int r0   = lr, r1 = 16 + lr;
    const int kby  = (lane >> 4) * 16;
    const int eb_  = tid >> 3;
    const int ecp  = (tid & 7) * 2;
    const int ecol = wg * 16 + ecp;

    // weights: load f32, convert, force resident
    bf16x8 wf[32];
    {
        const float* Wsrc = (role == 0) ? Wh0f : (role == 1) ? Wx1f : Wh1f;
        const float* p = Wsrc + (size_t)(wave * HID + wg * 16 + lr) * HID + lk8;
        #pragma unroll
        for (int kk = 0; kk < 32; ++kk) {
            float4 v0 = *(const float4*)(p + kk * 32);
            float4 v1 = *(const float4*)(p + kk * 32 + 4);
            union { bf16x8 v; unsigned short s[8]; } u;
            u.s[0] = f2bf(v0.x); u.s[1] = f2bf(v0.y);
            u.s[2] = f2bf(v0.z); u.s[3] = f2bf(v0.w);
            u.s[4] = f2bf(v1.x); u.s[5] = f2bf(v1.y);
            u.s[6] = f2bf(v1.z); u.s[7] = f2bf(v1.w);
            wf[kk] = u.v;
        }
        #pragma unroll
        for (int kk = 0; kk < 32; ++kk) asm volatile("" : "+v"(wf[kk]));
    }

    // stage 64KB h-slab from block layout into swizzled LDS image
    auto stage_g = [&](const unsigned short* src) {
        #pragma unroll
        for (int j = 0; j < 16; ++j) {
            int base = wave * 16384 + j * 1024;    // wave-uniform LDS dest
            int d = base + lane * 16;
            int r = d >> 11;
            int cb = (d & 2047) ^ ((r & 7) << 4);
            int e0 = cb >> 1;
            int g = (((e0 >> 4) * 32 + r) * 16 + (e0 & 15)) * 2;
            gload_lds16((const char*)src + g, smem + base);
        }
    };
    auto mm = [&](f32x4& A0, f32x4& A1) {
        #pragma unroll
        for (int kk = 0; kk < 32; ++kk) {
            int k2 = kk * 64 + kby;
            bf16x8 x0 = *(const bf16x8*)(smem + r0 * 2048 + (k2 ^ ((r0 & 7) << 4)));
            bf16x8 x1 = *(const bf16x8*)(smem + r1 * 2048 + (k2 ^ ((r1 & 7) << 4)));
            A0 = __builtin_amdgcn_mfma_f32_16x16x32_bf16(x0, wf[kk], A0, 0, 0, 0);
            A1 = __builtin_amdgcn_mfma_f32_16x16x32_bf16(x1, wf[kk], A1, 0, 0, 0);
        }
    };
    auto spill = [&](const f32x4& a0, const f32x4& a1) {
        float* pg = pre + wave * 512;
        #pragma unroll
        for (int j = 0; j < 4; ++j) {
            pg[((lane >> 4) * 4 + j) * 16 + lr]        = a0[j];
            pg[((lane >> 4) * 4 + j + 16) * 16 + lr]   = a1[j];
        }
    };
    // all-wave parallel poll: every wave checks all 64 flags of group `grp`
    auto pollge = [&](int grp, int val) {
        for (;;) {
            int f = __hip_atomic_load(&bar[(grp * 64 + lane) * 32],
                                      __ATOMIC_RELAXED, AGT);
            if (__all(f >= val)) break;
            __builtin_amdgcn_s_sleep(1);
        }
    };

    if (role == 0) {                               // ---------- L0 ----------
        float creg0, creg1;
        { float2 c2 = *(const float2*)&c0i[eb_ * HID + ecol]; creg0 = c2.x; creg1 = c2.y; }
        for (int t = 0; t < SEQT; ++t) {
            float2 gpre[4];
            const float* gxr = gx0 + (size_t)(t * BATCH + eb_) * GATES + ecol;
            #pragma unroll
            for (int g = 0; g < 4; ++g) gpre[g] = *(const float2*)(gxr + g * HID);
            if (t > 0) pollge(0, t);
            asm volatile("" ::: "memory");
            stage_g(t == 0 ? h0b : y0x + (size_t)(t - 1) * HSLAB);
            __syncthreads();
            f32x4 a0 = 0.f, a1 = 0.f;
            mm(a0, a1);
            spill(a0, a1);
            __syncthreads();
            float2 P[4];
            #pragma unroll
            for (int g = 0; g < 4; ++g) {
                float2 pr = *(const float2*)&pre[(g * 32 + eb_) * 16 + ecp];
                P[g].x = pr.x + gpre[g].x; P[g].y = pr.y + gpre[g].y;
            }
            float i0 = sigm(P[0].x), fg0 = sigm(P[1].x), o0 = sigm(P[2].x), n0 = tanhf(P[3].x);
            float i1 = sigm(P[0].y), fg1 = sigm(P[1].y), o1 = sigm(P[2].y), n1 = tanhf(P[3].y);
            float cn0 = fg0 * creg0 + i0 * n0, cn1 = fg1 * creg1 + i1 * n1;
            float hv0 = o0 * tanhf(cn0), hv1 = o1 * tanhf(cn1);
            creg0 = cn0; creg1 = cn1;
            unsigned pk = (unsigned)f2bf(hv0) | ((unsigned)f2bf(hv1) << 16);
            __hip_atomic_store(
                (unsigned*)&y0x[(size_t)t * HSLAB + (wg * 32 + eb_) * 16 + ecp],
                pk, __ATOMIC_RELAXED, AGT);
            if (t == SEQT - 1) {
                *(float2*)&h0f[eb_ * HID + ecol] = make_float2(hv0, hv1);
                *(float2*)&c0f[eb_ * HID + ecol] = make_float2(cn0, cn1);
            }
            __syncthreads();                       // drain publishes of all waves
            if (tid == 0)
                __hip_atomic_store(&bar[wg * 32], t + 1, __ATOMIC_RELAXED, AGT);
        }
    } else if (role == 1) {                        // ---------- L1x ----------
        for (int t = 0; t < SEQT; ++t) {
            pollge(0, t + 1);
            asm volatile("" ::: "memory");
            stage_g(y0x + (size_t)t * HSLAB);
            __syncthreads();
            f32x4 a0 = 0.f, a1 = 0.f;
            mm(a0, a1);
            {   // contiguous per-wave partial block [t][wave][wg][32][16]
                float* pb = part + (((size_t)(t * 4 + wave) * 64 + wg) * 32) * 16;
                int brow = (lane >> 4) * 4;
                #pragma unroll
                for (int j = 0; j < 4; ++j) {
                    __hip_atomic_store(pb + (brow + j) * 16 + lr,      a0[j],
                                       __ATOMIC_RELAXED, AGT);
                    __hip_atomic_store(pb + (brow + j + 16) * 16 + lr, a1[j],
                                       __ATOMIC_RELAXED, AGT);
                }
            }
            __syncthreads();
            if (tid == 0)
                __hip_atomic_store(&bar[(64 + wg) * 32], t + 1, __ATOMIC_RELAXED, AGT);
        }
    } else {                                       // ---------- L1h ----------
        float creg0, creg1;
        { float2 c2 = *(const float2*)&c1i[eb_ * HID + ecol]; creg0 = c2.x; creg1 = c2.y; }
        float2 b1r[4];
        #pragma unroll
        for (int g = 0; g < 4; ++g) {
            float2 a = *(const float2*)&bx1[g * HID + ecol];
            float2 b = *(const float2*)&bh1[g * HID + ecol];
            b1r[g].x = a.x + b.x; b1r[g].y = a.y + b.y;
        }
        for (int t = 0; t < SEQT; ++t) {
            pollge(1, t + 1);
            if (t > 0) pollge(2, t);
            asm volatile("" ::: "memory");
            stage_g(t == 0 ? h1b : y1x + (size_t)(t - 1) * HSLAB);
            __syncthreads();
            f32x4 a0 = 0.f, a1 = 0.f;
            mm(a0, a1);
            spill(a0, a1);
            __syncthreads();
            float2 P[4];
            #pragma unroll
            for (int g = 0; g < 4; ++g) {
                float2 pr = *(const float2*)&pre[(g * 32 + eb_) * 16 + ecp];
                float2 px = *(const float2*)(part +
                    ((((size_t)(t * 4 + g) * 64 + wg) * 32 + eb_) * 16 + ecp));
                P[g].x = pr.x + px.x + b1r[g].x;
                P[g].y = pr.y + px.y + b1r[g].y;
            }
            float i0 = sigm(P[0].x), fg0 = sigm(P[1].x), o0 = sigm(P[2].x), n0 = tanhf(P[3].x);
            float i1 = sigm(P[0].y), fg1 = sigm(P[1].y), o1 = sigm(P[2].y), n1 = tanhf(P[3].y);
            float cn0 = fg0 * creg0 + i0 * n0, cn1 = fg1 * creg1 + i1 * n1;
            float hv0 = o0 * tanhf(cn0), hv1 = o1 * tanhf(cn1);
            creg0 = cn0; creg1 = cn1;
            unsigned pk = (unsigned)f2bf(hv0) | ((unsigned)f2bf(hv1) << 16);
            __hip_atomic_store(
                (unsigned*)&y1x[(size_t)t * HSLAB + (wg * 32 + eb_) * 16 + ecp],
                pk, __ATOMIC_RELAXED, AGT);
            if (t == SEQT - 1) {
                *(float2*)&h1f[eb_ * HID + ecol] = make_float2(hv0, hv1);
                *(float2*)&c1f[eb_ * HID + ecol] = make_float2(cn0, cn1);
            }
            __syncthreads();
            if (tid == 0)
                __hip_atomic_store(&bar[(128 + wg) * 32], t + 1, __ATOMIC_RELAXED, AGT);
        }
    }
}

// ---------------- FC: 256x256 tiles, counted-vmcnt double-buffered pipeline ----------------
// (R12-proven) + non-temporal logits stores (write-once data, keep L2 for reuse).
__global__ __launch_bounds__(512) void fc_k(
    const unsigned short* __restrict__ y1x,
    const unsigned short* __restrict__ fcWb,
    const float* __restrict__ fcb,
    float* __restrict__ logits)
{
    __shared__ char smem[131072];
    const int tid  = threadIdx.x;
    const int lane = tid & 63;
    const int wave = tid >> 6;             // 0..7
    const int wr   = wave >> 2;            // 0..1 (M halves of 128)
    const int wc   = wave & 3;             // 0..3 (N quarters of 64)
    const int lr   = lane & 15;
    const int lk2  = (lane >> 4) * 16;     // byte offset of 8-elem k-group

    const int chunk = (int)blockIdx.x >> 3;            // 0..124
    const int wid   = ((int)blockIdx.x & 7) * 125 + chunk;
    const int bm    = (wid % 8) << 8;      // 8 M panels of 256
    const int bn    = (wid / 8) << 8;      // 125 N panels of 256

    // LDS: A(buf,half) at buf*32768 + half*16384; B at +65536.
    auto stage_half = [&](int hh, int kt, int buf) {
        #pragma unroll
        for (int i = 0; i < 2; ++i) {
            int ch = tid + i * 512;                    // 0..1023
            int row = ch >> 3, ck = ch & 7;
            int e = kt * 64 + ((ck ^ (row & 7)) << 3); // source-permuted k-granule
            if (hh < 2) {
                char* dst = smem + buf * 32768 + hh * 16384 + ch * 16;
                int R = bm + hh * 128 + row;
                const char* src = (const char*)y1x +
                    ((((size_t)(R >> 5) * 64 + (e >> 4)) * 32 + (R & 31)) * 16 + (e & 15)) * 2;
                gload_lds16(src, dst);
            } else {
                char* dst = smem + 65536 + buf * 32768 + (hh - 2) * 16384 + ch * 16;
                int R = bn + (hh - 2) * 128 + row;
                gload_lds16(fcWb + (size_t)R * HID + e, dst);
            }
        }
    };

    f32x4 acc[8][4];
    #pragma unroll
    for (int m = 0; m < 8; ++m)
        #pragma unroll
        for (int n = 0; n < 4; ++n) acc[m][n] = 0.f;

    bf16x8 bfr[4][2];
    auto ldb = [&](int buf) {
        const char* Bb = smem + 65536 + buf * 32768 + (wc >> 1) * 16384;
        #pragma unroll
        for (int n = 0; n < 4; ++n)
            #pragma unroll
            for (int kh = 0; kh < 2; ++kh) {
                int rB = (wc & 1) * 64 + n * 16 + lr;
                bfr[n][kh] = *(const bf16x8*)(Bb + rB * 128 +
                              ((kh * 64 + lk2) ^ ((rB & 7) << 4)));
            }
    };
    auto mgrp = [&](int buf, int g) {       // m-pair group g = 0..3
        const char* Ab = smem + buf * 32768 + wr * 16384;
        bf16x8 af[2][2];
        #pragma unroll
        for (int mi = 0; mi < 2; ++mi)
            #pragma unroll
            for (int kh = 0; kh < 2; ++kh) {
                int rA = (g * 2 + mi) * 16 + lr;
                af[mi][kh] = *(const bf16x8*)(Ab + rA * 128 +
                              ((kh * 64 + lk2) ^ ((rA & 7) << 4)));
            }
        __builtin_amdgcn_s_setprio(1);
        #pragma unroll
        for (int mi = 0; mi < 2; ++mi)
            #pragma unroll
            for (int n = 0; n < 4; ++n)
                #pragma unroll
                for (int kh = 0; kh < 2; ++kh)
                    acc[g * 2 + mi][n] = __builtin_amdgcn_mfma_f32_16x16x32_bf16(
                        af[mi][kh], bfr[n][kh], acc[g * 2 + mi][n], 0, 0, 0);
        __builtin_amdgcn_s_setprio(0);
    };

    // prologue: K-tile 0, all 4 halves -> buf 0   (8 loads/thread)
    stage_half(0, 0, 0); stage_half(1, 0, 0);
    stage_half(2, 0, 0); stage_half(3, 0, 0);

    int cbuf = 0;
    for (int kt = 0; kt < 15; ++kt) {
        MBAR();                                    // all prior reads of cbuf^1 done
        stage_half(0, kt + 1, cbuf ^ 1);           // +2 loads (newest)
        asm volatile("s_waitcnt vmcnt(2)" ::: "memory");   // all older (tile kt) landed
        __builtin_amdgcn_sched_barrier(0);
        MBAR();                                    // => landed for EVERY wave
        ldb(cbuf);
        stage_half(1, kt + 1, cbuf ^ 1);
        mgrp(cbuf, 0);
        stage_half(2, kt + 1, cbuf ^ 1);
        mgrp(cbuf, 1);
        stage_half(3, kt + 1, cbuf ^ 1);
        mgrp(cbuf, 2);
        mgrp(cbuf, 3);
        cbuf ^= 1;
    }
    // last K-tile: nothing left to prefetch -> full drain
    MBAR();
    asm volatile("s_waitcnt vmcnt(0)" ::: "memory");
    __builtin_amdgcn_sched_barrier(0);
    MBAR();
    ldb(cbuf);
    mgrp(cbuf, 0); mgrp(cbuf, 1); mgrp(cbuf, 2); mgrp(cbuf, 3);

    const int row0 = bm + wr * 128, col0 = bn + wc * 64;
    #pragma unroll
    for (int n = 0; n < 4; ++n) {
        int col = col0 + n * 16 + lr;
        float badd = fcb[col];
        #pragma unroll
        for (int m = 0; m < 8; ++m) {
            #pragma unroll
            for (int j = 0; j < 4; ++j) {
                int row = row0 + m * 16 + (lane >> 4) * 4 + j;
                __builtin_nontemporal_store(acc[m][n][j] + badd,
                                            &logits[(size_t)row * VOCAB + col]);
            }
        }
    }
}

extern "C" void kernel_launch(void* const* d_in, const int* in_sizes, int n_in,
                              void* d_out, int out_size, void* d_ws, size_t ws_size,
                              hipStream_t stream) {
    const int*   x    = (const int*)d_in[0];
    const float* embW = (const float*)d_in[1];
    const float* Wx0  = (const float*)d_in[2];
    const float* Wh0  = (const float*)d_in[3];
    const float* bx0  = (const float*)d_in[4];
    const float* bh0  = (const float*)d_in[5];
    const float* Wx1  = (const float*)d_in[6];
    const float* Wh1  = (const float*)d_in[7];
    const float* bx1  = (const float*)d_in[8];
    const float* bh1  = (const float*)d_in[9];
    const float* fcW  = (const float*)d_in[10];
    const float* fcb  = (const float*)d_in[11];
    const float* h0   = (const float*)d_in[12];
    const float* c0   = (const float*)d_in[13];
    const float* h1   = (const float*)d_in[14];
    const float* c1   = (const float*)d_in[15];

    char* ws = (char*)d_ws;
    size_t off = 0;
    auto alloc = [&](size_t bytes) {
        char* p = ws + off;
        off += (bytes + 255) & ~(size_t)255;
        return p;
    };
    unsigned short* eb    = (unsigned short*)alloc((size_t)ROWS * HID * 2);
    unsigned short* Wx0b  = (unsigned short*)alloc((size_t)GATES * HID * 2);
    unsigned short* fcWb  = (unsigned short*)alloc((size_t)VOCAB * HID * 2);
    float*          gx0   = (float*)alloc((size_t)ROWS * GATES * 4);
    float*          part  = (float*)alloc((size_t)SEQT * 4 * 64 * 32 * 16 * 4);
    unsigned short* y0x   = (unsigned short*)alloc((size_t)SEQT * HSLAB * 2);
    unsigned short* y1x   = (unsigned short*)alloc((size_t)SEQT * HSLAB * 2);
    unsigned short* h0b   = (unsigned short*)alloc((size_t)BATCH * HID * 2);
    unsigned short* h1b   = (unsigned short*)alloc((size_t)BATCH * HID * 2);
    int*            bar   = (int*)alloc((size_t)256 * 32 * 4);
    (void)ws_size; (void)in_sizes; (void)n_in; (void)out_size;

    float* logits = (float*)d_out;
    float* h0f = logits + (size_t)ROWS * VOCAB;
    float* c0f = h0f + BATCH * HID;
    float* h1f = c0f + BATCH * HID;
    float* c1f = h1f + BATCH * HID;

    // 1. fused prologue: embed + Wx0 cvt + state/flag init
    prologue_k<<<ROWS, 256, 0, stream>>>(x, embW, eb, Wx0, Wx0b,
                                         h0, h1, h0b, h1b, bar);
    // 2. gx0 = e @ Wx0^T + (bx0+bh0)  (256x128 counted-vmcnt pipeline)
    gemm_bt<<<256, 512, 0, stream>>>(eb, Wx0b, gx0, bx0, bh0);
    // 3. persistent recurrence, XCD-local roles (+ fcW convert on spare CUs)
    lstm_fused_k<<<256, 256, 0, stream>>>(Wh0, Wx1, Wh1, gx0, bx1, bh1,
                                          h0b, h1b, c0, c1, y0x, y1x, part,
                                          h0f, c0f, h1f, c1f, bar, fcW, fcWb);
    // 4. logits = y1 @ fcW^T + fc_b  (256x256 counted-vmcnt pipeline, nt stores)
    fc_k<<<1000, 512, 0, stream>>>(y1x, fcWb, fcb, logits);
}